// Round 14
// baseline (5342.722 us; speedup 1.0000x reference)
//
#include <hip/hip_runtime.h>

// Packed-LSTM (B=64, S=2048, H=512, V=25) + final linear head.
// R13 base (best headline 5247 us) + HEATER BLOCKS (DVFS test). Workers:
// 4 groups of 16 batches; 16 WGs/group x 256 thr; WG owns 32 hidden units;
// W_hh slice in VGPRs as bf16 MFMA B-frags; per step MFMA [16x512]@[512x128]
// + fp32 cell. Exchange: self-tagged qwords, parity double buffer, agent
// scope + XCD-local sc0 fast path with representative-poll (R13; FETCH
// -40% proven L2-serviced, latency equal -> exchange axis closed).
//
// NEW: blocks bid>=128 are HEATERS - pure 4-chain FMA spin (~100% VALU
// issue, no memory traffic) on every XCD until group 0 (global-max length,
// always the last finisher) sets a done flag. Hypothesis: at ~2% chip
// utilization the power governor parks sclk far below fmax, inflating the
// serial store->visible->detect chain ~1.6x in wall time (first-dispatch
// 26-52ms ramp signature supports this). Heaters keep sclk boosted without
// touching the workers' critical path. Hard iteration bound guarantees
// heater exit even if the flag store is lost.

#define VOCAB 25
#define HIDDEN 512
#define BATCH 64
#define SEQ 2048
#define GB 16    // batches per group
#define NG 4     // groups
#define WPG 16   // workgroups per group
#define HSL 32   // hidden units per WG
#define RWG 128  // gate rows per WG = 4*HSL
#define NTHREADS 256
#define HGQ (GB * HIDDEN / 2)  // 4096 tagged qwords per group parity buffer
#define RC_INTS 1024           // 4 KB roll-call region (int 512 = done flag)
#define REP_BUDGET 1024        // rep-poll iters before demote (per step)
#define FF_BUDGET 256          // full-fetch iters before demote

typedef short s16x8 __attribute__((ext_vector_type(8)));
typedef float f32x4 __attribute__((ext_vector_type(4)));
typedef unsigned long long ull;

__device__ inline unsigned short f2bf(float x) {
  unsigned u = __float_as_uint(x);
  u += 0x7fffu + ((u >> 16) & 1u);  // RNE
  return (unsigned short)(u >> 16);
}
__device__ inline float sigf(float x) { return 1.0f / (1.0f + __expf(-x)); }
__device__ inline float tanh_fast(float x) { return 2.0f / (1.0f + __expf(-2.0f * x)) - 1.0f; }

__global__ void prep_kernel(int* rc, ull* hgA, ull* hgL, int allow_l2, float* out) {
  const int i = blockIdx.x * blockDim.x + threadIdx.x;
  const int n = blockDim.x * gridDim.x;
  for (int k = i; k < RC_INTS; k += n) rc[k] = 0;
  for (int k = i; k < 2 * NG * HGQ; k += n) hgA[k] = 0ull;  // tag 0 never matches
  if (allow_l2)
    for (int k = i; k < 2 * NG * HGQ; k += n) hgL[k] = 0ull;
  if (i < BATCH) out[i] = 0.f;
}

__global__ __launch_bounds__(NTHREADS, 1) void lstm_persistent(
    const int* __restrict__ tokens, const int* __restrict__ lengths,
    const float* __restrict__ W_ih, const float* __restrict__ W_hh,
    const float* __restrict__ b_ih, const float* __restrict__ b_hh,
    const float* __restrict__ fc_w, const float* __restrict__ fc_b,
    float* __restrict__ out, int* rc, ull* hgA, ull* hgL, int allow_l2) {
  const int tid = threadIdx.x;
  const int bid = blockIdx.x;

  if (bid >= 128) {  // ---- HEATER: saturate VALU until workers finish ----
    float a0 = (float)tid + 1.0f, a1 = a0 * 1.1f, a2 = a0 * 1.2f, a3 = a0 * 1.3f;
    const float c = 1.0000001f, d = 1e-9f;
    for (int it = 0; it < 1000000; ++it) {  // hard bound ~27ms @2.4GHz
#pragma unroll
      for (int u = 0; u < 16; ++u) {
        a0 = __builtin_fmaf(a0, c, d);
        a1 = __builtin_fmaf(a1, c, d);
        a2 = __builtin_fmaf(a2, c, d);
        a3 = __builtin_fmaf(a3, c, d);
      }
      if ((it & 255) == 0 &&
          __hip_atomic_load(&rc[512], __ATOMIC_RELAXED, __HIP_MEMORY_SCOPE_AGENT))
        break;
    }
    asm volatile("" ::"v"(a0), "v"(a1), "v"(a2), "v"(a3));  // keep live (no DCE)
    return;
  }

  const int x = bid & 7;
  if (x & 1) return;       // odd residues idle (placement spacer)
  const int g = x >> 1;    // group 0..3 -> residue 2g -> one XCD if RR holds
  const int w = bid >> 3;  // wg-in-group 0..15

  __shared__ __align__(16) unsigned short hbuf[GB][HIDDEN + 8];  // bf16 h, padded
  __shared__ float gatesb[GB][RWG + 5];
  __shared__ float xgt[VOCAB][RWG + 5];
  __shared__ int lenAll[BATCH];
  __shared__ int order_[BATCH];
  __shared__ int gIdx[GB];
  __shared__ int gLen[GB];
  __shared__ int rcsh[WPG];

  // publish roll-call entry early (overlaps init)
  unsigned xcc;
  asm volatile("s_getreg_b32 %0, hwreg(20, 0, 32)" : "=s"(xcc));  // HW_REG_XCC_ID
  xcc &= 0xFu;
  if (tid == 0)
    __hip_atomic_store(&rc[g * WPG + w], (int)(0x100u | xcc), __ATOMIC_RELAXED,
                       __HIP_MEMORY_SCOPE_AGENT);

  if (tid < BATCH) lenAll[tid] = lengths[tid];
  __syncthreads();
  if (tid < BATCH) {  // stable argsort(-lengths): rank by count
    const int L = lenAll[tid];
    int r = 0;
    for (int j = 0; j < BATCH; ++j) {
      const int lj = lenAll[j];
      r += ((lj > L) || (lj == L && j < tid)) ? 1 : 0;
    }
    order_[r] = tid;
  }
  __syncthreads();
  if (tid < GB) {
    const int oi = order_[g * GB + tid];
    gIdx[tid] = oi;
    gLen[tid] = lenAll[oi];
  }
  for (int i = tid; i < GB * (HIDDEN + 8); i += NTHREADS)
    ((unsigned short*)hbuf)[i] = 0;  // h0 = 0
  for (int i = tid; i < VOCAB * RWG; i += NTHREADS) {
    const int v = i / RWG, rl = i % RWG;
    const int rg = (rl >> 5) * HIDDEN + w * HSL + (rl & 31);
    xgt[v][rl] = W_ih[rg * VOCAB + v] + b_ih[rg] + b_hh[rg];
  }

  // roll-call gather: all 16 members' XCC ids
  if (tid < WPG) {
    int v;
    do {
      v = __hip_atomic_load(&rc[g * WPG + tid], __ATOMIC_RELAXED,
                            __HIP_MEMORY_SCOPE_AGENT);
    } while (!(v & 0x100));
    rcsh[tid] = v & 0xF;
  }
  __syncthreads();
  bool uni = true;
#pragma unroll
  for (int j = 0; j < WPG; ++j) uni &= (rcsh[j] == rcsh[0]);
  const bool l2grp = uni && (allow_l2 != 0);

  const int T = gLen[0];  // group maxlen (sorted descending)
  const int lane = tid & 63;
  const int wv = tid >> 6;
  const int m16 = lane & 15;
  const int quad = lane >> 4;

  // B fragments (bf16 W_hh slice) in VGPRs: wave wv owns ntiles {wv, wv+4}.
  s16x8 Bf[2][16];
#pragma unroll
  for (int nti = 0; nti < 2; ++nti) {
    const int nt = wv + 4 * nti;
    const int rl = nt * 16 + m16;  // local gate-row 0..127
    const int rg = (rl >> 5) * HIDDEN + w * HSL + (rl & 31);
    const float* wr = W_hh + (size_t)rg * HIDDEN;
#pragma unroll
    for (int kt = 0; kt < 16; ++kt) {
      const float* p = wr + kt * 32 + quad * 8;
#pragma unroll
      for (int e = 0; e < 8; ++e) Bf[nti][kt][e] = (short)f2bf(p[e]);
    }
  }

  // Cell state: thread (cb,cs) owns hidden units jj0,jj1 of batch cb.
  const int cb = tid >> 4;
  const int cs = tid & 15;
  const int jj0 = 2 * cs, jj1 = 2 * cs + 1;
  const int myLen = gLen[cb];
  const int* tokRow = tokens + (size_t)gIdx[cb] * SEQ;
  ull* const baseA0 = hgA + (size_t)g * HGQ;         // agent parity 0
  ull* const baseA1 = hgA + (size_t)(NG + g) * HGQ;  // agent parity 1
  ull* const l2b0 = hgL + (size_t)g * HGQ;           // L2 parity 0
  ull* const l2b1 = hgL + (size_t)(NG + g) * HGQ;    // L2 parity 1

  // poll voffsets: vo[j] covers producers r=2j (imm 0), r=2j+1 (imm 2048)
  unsigned vo[8];
#pragma unroll
  for (int j = 0; j < 8; ++j) vo[j] = (unsigned)(tid * 8 + j * 4096);
  const int rep = (w + 8) & 15;  // fixed non-self representative producer
  const unsigned voRep = (unsigned)((rep * 256 + tid) * 8);
  const unsigned voS = (unsigned)((w * 256 + tid) * 8);  // producer store offset

  bool l2m = l2grp;  // consumer path (sticky-demotable, wave-uniform)
  float c0 = 0.f, c1 = 0.f, h0 = 0.f, h1 = 0.f;

  for (int t = 0; t < T; ++t) {
    const int tok = tokRow[t];  // issued before the poll; latency hidden

    if (t > 0) {
      ull q[16];
      bool got = false;
      if (l2m) {
        const ull* lb = (t & 1) ? l2b1 : l2b0;
        // light representative poll: 1 sc0 load per thread per iteration
        bool hit = false;
        int iters = 0;
        for (;;) {
          ull rq;
          asm volatile(
              "global_load_dwordx2 %0, %1, %2 sc0\n\t"
              "s_waitcnt vmcnt(0)"
              : "=&v"(rq) : "v"(voRep), "s"(lb) : "memory");
          __builtin_amdgcn_sched_barrier(0);
          if (__all((unsigned)(rq >> 32) == (unsigned)t)) { hit = true; break; }
          if (++iters > REP_BUDGET) break;
          __builtin_amdgcn_s_sleep(1);
        }
        if (hit) {  // full fetch (usually 1 iteration)
          int fi = 0;
          for (;;) {
            asm volatile(
                "global_load_dwordx2 %[q0],  %[o0], %[b] sc0\n\t"
                "global_load_dwordx2 %[q1],  %[o0], %[b] offset:2048 sc0\n\t"
                "global_load_dwordx2 %[q2],  %[o1], %[b] sc0\n\t"
                "global_load_dwordx2 %[q3],  %[o1], %[b] offset:2048 sc0\n\t"
                "global_load_dwordx2 %[q4],  %[o2], %[b] sc0\n\t"
                "global_load_dwordx2 %[q5],  %[o2], %[b] offset:2048 sc0\n\t"
                "global_load_dwordx2 %[q6],  %[o3], %[b] sc0\n\t"
                "global_load_dwordx2 %[q7],  %[o3], %[b] offset:2048 sc0\n\t"
                "global_load_dwordx2 %[q8],  %[o4], %[b] sc0\n\t"
                "global_load_dwordx2 %[q9],  %[o4], %[b] offset:2048 sc0\n\t"
                "global_load_dwordx2 %[q10], %[o5], %[b] sc0\n\t"
                "global_load_dwordx2 %[q11], %[o5], %[b] offset:2048 sc0\n\t"
                "global_load_dwordx2 %[q12], %[o6], %[b] sc0\n\t"
                "global_load_dwordx2 %[q13], %[o6], %[b] offset:2048 sc0\n\t"
                "global_load_dwordx2 %[q14], %[o7], %[b] sc0\n\t"
                "global_load_dwordx2 %[q15], %[o7], %[b] offset:2048 sc0\n\t"
                "s_waitcnt vmcnt(0)"
                : [q0] "=&v"(q[0]), [q1] "=&v"(q[1]), [q2] "=&v"(q[2]),
                  [q3] "=&v"(q[3]), [q4] "=&v"(q[4]), [q5] "=&v"(q[5]),
                  [q6] "=&v"(q[6]), [q7] "=&v"(q[7]), [q8] "=&v"(q[8]),
                  [q9] "=&v"(q[9]), [q10] "=&v"(q[10]), [q11] "=&v"(q[11]),
                  [q12] "=&v"(q[12]), [q13] "=&v"(q[13]), [q14] "=&v"(q[14]),
                  [q15] "=&v"(q[15])
                : [o0] "v"(vo[0]), [o1] "v"(vo[1]), [o2] "v"(vo[2]),
                  [o3] "v"(vo[3]), [o4] "v"(vo[4]), [o5] "v"(vo[5]),
                  [o6] "v"(vo[6]), [o7] "v"(vo[7]), [b] "s"(lb)
                : "memory");
            __builtin_amdgcn_sched_barrier(0);
            bool ok = true;
#pragma unroll
            for (int r = 0; r < 16; ++r)
              ok &= ((unsigned)(q[r] >> 32) == (unsigned)t);
            if (__all(ok)) { got = true; break; }
            if (++fi > FF_BUDGET) break;
            __builtin_amdgcn_s_sleep(1);
          }
        }
        if (!got) l2m = false;  // sticky, wave-uniform demotion
      }
      if (!got) {
        // agent-scope spin (R2 protocol; always correct)
        const ull* src = ((t & 1) ? baseA1 : baseA0) + tid;
        for (;;) {
          bool ok = true;
#pragma unroll
          for (int r = 0; r < 16; ++r)
            q[r] = __hip_atomic_load(src + r * 256, __ATOMIC_RELAXED,
                                     __HIP_MEMORY_SCOPE_AGENT);
#pragma unroll
          for (int r = 0; r < 16; ++r)
            ok &= ((unsigned)(q[r] >> 32) == (unsigned)t);
          if (ok) break;
        }
      }
      // Scatter payloads into LDS: producer r's units r*32+2cs, r*32+2cs+1.
#pragma unroll
      for (int r = 0; r < 16; ++r)
        *(unsigned*)&hbuf[cb][r * 32 + jj0] = (unsigned)q[r];
    }
    __syncthreads();  // hbuf[t] staged

    // gates slice = h[16x512] @ Wslice^T[512x128] via MFMA 16x16x32 bf16.
    f32x4 acc0a = {0.f, 0.f, 0.f, 0.f}, acc0b = {0.f, 0.f, 0.f, 0.f};
    f32x4 acc1a = {0.f, 0.f, 0.f, 0.f}, acc1b = {0.f, 0.f, 0.f, 0.f};
#pragma unroll
    for (int kt = 0; kt < 16; kt += 2) {
      const s16x8 A0 = *(const s16x8*)&hbuf[m16][kt * 32 + quad * 8];
      const s16x8 A1 = *(const s16x8*)&hbuf[m16][(kt + 1) * 32 + quad * 8];
      acc0a = __builtin_amdgcn_mfma_f32_16x16x32_bf16(A0, Bf[0][kt], acc0a, 0, 0, 0);
      acc1a = __builtin_amdgcn_mfma_f32_16x16x32_bf16(A0, Bf[1][kt], acc1a, 0, 0, 0);
      acc0b = __builtin_amdgcn_mfma_f32_16x16x32_bf16(A1, Bf[0][kt + 1], acc0b, 0, 0, 0);
      acc1b = __builtin_amdgcn_mfma_f32_16x16x32_bf16(A1, Bf[1][kt + 1], acc1b, 0, 0, 0);
    }
    const f32x4 acc0 = acc0a + acc0b;
    const f32x4 acc1 = acc1a + acc1b;
    // D layout: col(n)=lane&15, row(m)=quad*4+v
#pragma unroll
    for (int v = 0; v < 4; ++v) {
      gatesb[quad * 4 + v][wv * 16 + m16] = acc0[v];
      gatesb[quad * 4 + v][(wv + 4) * 16 + m16] = acc1[v];
    }
    __syncthreads();  // gates ready; also fences hbuf reads vs next-iter staging

    // LSTM cell update (fp32), frozen past sequence end
    const float pi0 = gatesb[cb][jj0] + xgt[tok][jj0];
    const float pf0 = gatesb[cb][32 + jj0] + xgt[tok][32 + jj0];
    const float pg0 = gatesb[cb][64 + jj0] + xgt[tok][64 + jj0];
    const float po0 = gatesb[cb][96 + jj0] + xgt[tok][96 + jj0];
    const float pi1 = gatesb[cb][jj1] + xgt[tok][jj1];
    const float pf1 = gatesb[cb][32 + jj1] + xgt[tok][32 + jj1];
    const float pg1 = gatesb[cb][64 + jj1] + xgt[tok][64 + jj1];
    const float po1 = gatesb[cb][96 + jj1] + xgt[tok][96 + jj1];
    if (t < myLen) {
      const float i0 = sigf(pi0), f0 = sigf(pf0), g0 = tanh_fast(pg0), o0 = sigf(po0);
      c0 = f0 * c0 + i0 * g0;
      h0 = o0 * tanh_fast(c0);
      const float i1 = sigf(pi1), f1 = sigf(pf1), g1 = tanh_fast(pg1), o1 = sigf(po1);
      c1 = f1 * c1 + i1 * g1;
      h1 = o1 * tanh_fast(c1);
    }
    if (t + 1 < T) {  // publish h for step t+1: tagged qword, dual path
      const unsigned payload = (unsigned)f2bf(h0) | ((unsigned)f2bf(h1) << 16);
      const ull qv = ((ull)(unsigned)(t + 1) << 32) | payload;
      if (l2grp) {  // fast path: sc0 store stays in this XCD's L2
        const ull* ldst = (((t + 1) & 1) ? l2b1 : l2b0);
        asm volatile("global_store_dwordx2 %0, %1, %2 sc0"
                     :: "v"(voS), "v"(qv), "s"(ldst) : "memory");
      }
      ull* hp = (((t + 1) & 1) ? baseA1 : baseA0) + w * 256 + tid;
      __hip_atomic_store(hp, qv, __ATOMIC_RELAXED, __HIP_MEMORY_SCOPE_AGENT);
    }
  }

  // out[p] = h . fc_w + fc_b, p = sorted position
  float part = h0 * fc_w[w * HSL + jj0] + h1 * fc_w[w * HSL + jj1];
  part += __shfl_down(part, 8, 16);
  part += __shfl_down(part, 4, 16);
  part += __shfl_down(part, 2, 16);
  part += __shfl_down(part, 1, 16);
  if (cs == 0) {
    if (w == 0) part += fc_b[0];
    atomicAdd(&out[g * GB + cb], part);
  }

  // group 0 has the global max length -> finishes last -> release heaters
  if (g == 0 && tid == 0)
    __hip_atomic_store(&rc[512], 1, __ATOMIC_RELAXED, __HIP_MEMORY_SCOPE_AGENT);
}

extern "C" void kernel_launch(void* const* d_in, const int* in_sizes, int n_in,
                              void* d_out, int out_size, void* d_ws, size_t ws_size,
                              hipStream_t stream) {
  (void)in_sizes; (void)n_in; (void)out_size;
  const int* tokens = (const int*)d_in[0];
  const int* lengths = (const int*)d_in[1];
  const float* W_ih = (const float*)d_in[2];
  const float* W_hh = (const float*)d_in[3];
  const float* b_ih = (const float*)d_in[4];
  const float* b_hh = (const float*)d_in[5];
  const float* fc_w = (const float*)d_in[6];
  const float* fc_b = (const float*)d_in[7];
  float* out = (float*)d_out;

  // workspace layout: [4KB rollcall+flag][256KB agent hg][256KB L2 hg]
  int* rc = (int*)d_ws;
  ull* hgA = (ull*)((char*)d_ws + 4096);
  ull* hgL = (ull*)((char*)d_ws + 4096 + 2 * NG * HGQ * sizeof(ull));
  const int allow_l2 = (ws_size >= 4096 + 4ull * NG * HGQ * sizeof(ull)) ? 1 : 0;

  prep_kernel<<<32, 256, 0, stream>>>(rc, hgA, hgL, allow_l2, out);
  lstm_persistent<<<384, NTHREADS, 0, stream>>>(tokens, lengths, W_ih, W_hh, b_ih,
                                                b_hh, fc_w, fc_b, out, rc, hgA, hgL,
                                                allow_l2);
}